// Round 5
// baseline (165.976 us; speedup 1.0000x reference)
//
#include <hip/hip_runtime.h>

#define IN_DIM 128
#define OUT_DIM 32
#define DEG 16
#define EPS 1e-8f
#define TN 64   // nodes per K1 block
#define S4 65   // float4 row stride of [k4][node] LDS tile (odd -> conflict-free reads)

// ds_swizzle xor-mask patterns (BitMode: (xor<<10)|0x1F), 32-lane domain
#define SWZ(x, p) __int_as_float(__builtin_amdgcn_ds_swizzle(__float_as_int(x), (p)))

static __device__ __forceinline__ unsigned f2bf(float x) {  // RNE f32->bf16
  unsigned u = __float_as_uint(x);
  u += 0x7FFFu + ((u >> 16) & 1u);
  return u >> 16;
}
static __device__ __forceinline__ float bflo(unsigned u) { return __uint_as_float(u << 16); }
static __device__ __forceinline__ float bfhi(unsigned u) { return __uint_as_float(u & 0xFFFF0000u); }

// Kernel 1: zh_bf16 = normalize(h @ W^T) rows (bf16), nrm = true row norms (f32).
// Tile 64 nodes/block. h staged in LDS TRANSPOSED [k4][node] (float4, stride 65):
// compute reads are lane-consecutive ds_read_b128 (conflict-free). Wave w owns
// outputs [8w,8w+8); W read at contiguous 16B wave-uniform addresses ->
// s_load_dwordx4+ merged by the compiler (no 512B-strided scalar dribble).
__global__ __launch_bounds__(256) void gemm_norm_kernel(
    const float* __restrict__ h, const float* __restrict__ W,
    unsigned short* __restrict__ zhb, float* __restrict__ nrm, int N) {
  __shared__ float4 sh4[32 * S4];  // 33.3 KB
  __shared__ float ssq[4][TN];

  const int tid = threadIdx.x;
  const int nb = blockIdx.x * TN;

  {  // stage: thread t -> k4 = t&31 (coalesced global), row r = t>>5, 8 rows apart
    const int k4 = tid & 31, r0 = tid >> 5;
    const float4* __restrict__ hg = (const float4*)h;
#pragma unroll
    for (int i = 0; i < 8; ++i) {
      const int n = r0 + i * 8;
      int gn = nb + n;
      if (gn >= N) gn = N - 1;  // clamped read; stores guarded below
      sh4[k4 * S4 + n] = hg[(size_t)gn * 32 + k4];
    }
  }
  __syncthreads();

  const int w = tid >> 6;   // wave id 0..3 (wave-uniform)
  const int l = tid & 63;   // lane = node in tile
  const int node = nb + l;
  const float* __restrict__ wb = W + (size_t)(w * 8) * IN_DIM;

  float acc[8] = {0.f, 0.f, 0.f, 0.f, 0.f, 0.f, 0.f, 0.f};
#pragma unroll 4
  for (int k4 = 0; k4 < 32; ++k4) {
    const float4 hv = sh4[k4 * S4 + l];  // ds_read_b128, conflict-free
#pragma unroll
    for (int j = 0; j < 8; ++j) {
      const float* __restrict__ wr = wb + j * IN_DIM + k4 * 4;  // uniform, 16B run
      acc[j] = fmaf(hv.x, wr[0], acc[j]);
      acc[j] = fmaf(hv.y, wr[1], acc[j]);
      acc[j] = fmaf(hv.z, wr[2], acc[j]);
      acc[j] = fmaf(hv.w, wr[3], acc[j]);
    }
  }

  float ssp = 0.f;
#pragma unroll
  for (int j = 0; j < 8; ++j) ssp = fmaf(acc[j], acc[j], ssp);
  ssq[w][l] = ssp;
  __syncthreads();
  const float ss = ssq[0][l] + ssq[1][l] + ssq[2][l] + ssq[3][l];
  const float ns = sqrtf(ss);
  const float inv = 1.0f / fmaxf(ns, EPS);

  if (node < N) {
    unsigned p0 = f2bf(acc[0] * inv) | (f2bf(acc[1] * inv) << 16);
    unsigned p1 = f2bf(acc[2] * inv) | (f2bf(acc[3] * inv) << 16);
    unsigned p2 = f2bf(acc[4] * inv) | (f2bf(acc[5] * inv) << 16);
    unsigned p3 = f2bf(acc[6] * inv) | (f2bf(acc[7] * inv) << 16);
    uint4* zp = (uint4*)(zhb + (size_t)node * OUT_DIM + w * 8);
    *zp = make_uint4(p0, p1, p2, p3);
    if (w == 0) nrm[node] = ns;
  }
}

// Kernel 2: half-wave per node; lane = (edge e = l5>>1, chunk c = l5&1 of 16
// outputs). Gathers are bf16 (32 B/lane: two dwordx4) -> half the L2/LLC
// traffic of f32; 6.4 MB table mostly L2-resident. cos = dot(zhat_s, zhat_d)
// (rows pre-normalized with eps clamp). Dot: 16 fma + ONE swizzle; denom: 4
// swizzles; edge->output transpose via private per-node LDS slot (same-wave,
// no barrier). Scores beta*(cos-1) in [-2b,0] -> no softmax max pass.
__global__ __launch_bounds__(256) void edge_kernel(
    const unsigned short* __restrict__ zhb, const float* __restrict__ nrm,
    const int* __restrict__ src, const float* __restrict__ beta_p,
    float* __restrict__ out, int N) {
  __shared__ float xp[8 * DEG * 36];  // 8 node-slots x 16e x stride36 = 18 KB

  const int tid = threadIdx.x;
  const int l5 = tid & 31, half = (tid >> 5) & 1, wv = tid >> 6;
  const int gw = blockIdx.x * 4 + wv;
  if (gw * 2 >= N) return;             // whole-wave uniform exit
  const int n = gw * 2 + half;
  const int ne = (n < N) ? n : N - 1;  // clamp loads; store guarded
  const int e = l5 >> 1, c = l5 & 1;

  const float beta = *beta_p;
  const int se = src[(size_t)ne * DEG + e];  // pair-dup, coalesced
  const float nrm_s = nrm[se];

  const uint4* zs4 = (const uint4*)(zhb + (size_t)se * OUT_DIM) + c * 2;
  const uint4 sa = zs4[0], sb = zs4[1];      // 16 bf16 of src row chunk c
  const uint4* zd4 = (const uint4*)(zhb + (size_t)ne * OUT_DIM) + c * 2;
  const uint4 da = zd4[0], db = zd4[1];      // 16 bf16 of dst row chunk c

  float vs[16];
  vs[0] = bflo(sa.x);  vs[1] = bfhi(sa.x);  vs[2] = bflo(sa.y);  vs[3] = bfhi(sa.y);
  vs[4] = bflo(sa.z);  vs[5] = bfhi(sa.z);  vs[6] = bflo(sa.w);  vs[7] = bfhi(sa.w);
  vs[8] = bflo(sb.x);  vs[9] = bfhi(sb.x);  vs[10] = bflo(sb.y); vs[11] = bfhi(sb.y);
  vs[12] = bflo(sb.z); vs[13] = bfhi(sb.z); vs[14] = bflo(sb.w); vs[15] = bfhi(sb.w);
  float vd[16];
  vd[0] = bflo(da.x);  vd[1] = bfhi(da.x);  vd[2] = bflo(da.y);  vd[3] = bfhi(da.y);
  vd[4] = bflo(da.z);  vd[5] = bfhi(da.z);  vd[6] = bflo(da.w);  vd[7] = bfhi(da.w);
  vd[8] = bflo(db.x);  vd[9] = bfhi(db.x);  vd[10] = bflo(db.y); vd[11] = bfhi(db.y);
  vd[12] = bflo(db.z); vd[13] = bfhi(db.z); vd[14] = bflo(db.w); vd[15] = bfhi(db.w);

  float p = vs[0] * vd[0];
#pragma unroll
  for (int i = 1; i < 16; ++i) p = fmaf(vs[i], vd[i], p);
  p += SWZ(p, 0x041F);  // xor1: add other 16-chunk -> full dot = cos

  const float ex = __expf(beta * (p - 1.0f));

  float den = ex;
  den += SWZ(den, 0x081F);  // xor2
  den += SWZ(den, 0x101F);  // xor4
  den += SWZ(den, 0x201F);  // xor8
  den += SWZ(den, 0x401F);  // xor16 -> sum over 16 edges
  const float rd = 1.0f / den;

  const float sc = ex * nrm_s;  // weight x un-normalization of zs
  float* slot = xp + (wv * 2 + half) * (DEG * 36);
  float4* wp = (float4*)(slot + e * 36 + c * 16);
  wp[0] = make_float4(sc * vs[0], sc * vs[1], sc * vs[2], sc * vs[3]);
  wp[1] = make_float4(sc * vs[4], sc * vs[5], sc * vs[6], sc * vs[7]);
  wp[2] = make_float4(sc * vs[8], sc * vs[9], sc * vs[10], sc * vs[11]);
  wp[3] = make_float4(sc * vs[12], sc * vs[13], sc * vs[14], sc * vs[15]);
  // same-wave LDS RAW: compiler inserts lgkmcnt wait, no barrier needed

  float s = 0.f;
#pragma unroll
  for (int e2 = 0; e2 < DEG; ++e2)
    s += slot[e2 * 36 + l5];  // bank (4e2+l5)%32: conflict-free

  if (n < N) out[(size_t)n * OUT_DIM + l5] = s * rd;  // coalesced
}

extern "C" void kernel_launch(void* const* d_in, const int* in_sizes, int n_in,
                              void* d_out, int out_size, void* d_ws, size_t ws_size,
                              hipStream_t stream) {
  const float* h    = (const float*)d_in[0];
  const float* W    = (const float*)d_in[1];
  const float* beta = (const float*)d_in[2];
  const int*   src  = (const int*)d_in[3];
  // d_in[4] = dst == arange(E)//DEG -> node n owns edges [n*DEG, (n+1)*DEG)

  const int N = in_sizes[0] / IN_DIM;

  unsigned short* zhb = (unsigned short*)d_ws;          // N*32 bf16 = 6.4 MB
  float* nrm = (float*)(zhb + (size_t)N * OUT_DIM);     // N floats

  const int bl1 = (N + TN - 1) / TN;
  gemm_norm_kernel<<<bl1, 256, 0, stream>>>(h, W, zhb, nrm, N);

  const int bl2 = ((N + 1) / 2 + 3) / 4;  // 2 nodes/wave, 4 waves/block
  edge_kernel<<<bl2, 256, 0, stream>>>(zhb, nrm, src, beta, (float*)d_out, N);
}

// Round 6
// 136.975 us; speedup vs baseline: 1.2117x; 1.2117x over previous
//
#include <hip/hip_runtime.h>

#define IN_DIM 128
#define OUT_DIM 32
#define DEG 16
#define EPS 1e-8f

typedef __attribute__((ext_vector_type(8))) short bf16x8;
typedef __attribute__((ext_vector_type(4))) float f32x4;

// ds_swizzle xor-mask patterns (BitMode: (xor<<10)|0x1F), 32-lane domain
#define SWZ(x, p) __int_as_float(__builtin_amdgcn_ds_swizzle(__float_as_int(x), (p)))

static __device__ __forceinline__ unsigned short f2bf(float x) {  // RNE f32->bf16
  unsigned u = __float_as_uint(x);
  u += 0x7FFFu + ((u >> 16) & 1u);
  return (unsigned short)(u >> 16);
}
static __device__ __forceinline__ float bflo(unsigned u) { return __uint_as_float(u << 16); }
static __device__ __forceinline__ float bfhi(unsigned u) { return __uint_as_float(u & 0xFFFF0000u); }

static __device__ __forceinline__ bf16x8 pack8(float4 a, float4 b) {
  bf16x8 r;
  r[0] = (short)f2bf(a.x); r[1] = (short)f2bf(a.y);
  r[2] = (short)f2bf(a.z); r[3] = (short)f2bf(a.w);
  r[4] = (short)f2bf(b.x); r[5] = (short)f2bf(b.y);
  r[6] = (short)f2bf(b.z); r[7] = (short)f2bf(b.w);
  return r;
}

// Kernel 1 (MFMA): z_bf16 = h @ W^T (raw), inv_nrm = 1/max(||z||_f32, eps).
// Block = 4 waves = 32 nodes. Wave (ng = w>>1, oh = w&1) computes nodes
// [mb,mb+16) x outs [16*oh,+16) with mfma_f32_16x16x32_bf16, K=128 in 4 chunks.
// A-frag: lane holds h[mb + (l&15)][32c + (l>>4)*8 + j]; B-frag: W[16*oh+(l&15)][same k].
// C/D: col=l&15 (out), row=(l>>4)*4+reg (node). No scalar loads, no LDS in K-loop
// (R5 lesson: s_load + ds_read mixing forces lgkmcnt(0) serialization).
__global__ __launch_bounds__(256) void gemm_norm_kernel(
    const float* __restrict__ h, const float* __restrict__ W,
    unsigned short* __restrict__ zhb, float* __restrict__ invn, int N) {
  __shared__ float pss[2][32];

  const int tid = threadIdx.x;
  const int wv = tid >> 6;
  const int l = tid & 63;
  const int n16 = l & 15;  // A row (node) / B col (out) lane index
  const int q = l >> 4;    // quad
  const int ng = wv >> 1, oh = wv & 1;
  const int mb = blockIdx.x * 32 + ng * 16;

  // B fragments (W is 16 KB, L1/L3-hot; 4 redundant reads per block are cheap)
  bf16x8 bfr[4];
  {
    const float* wr = W + (size_t)(oh * 16 + n16) * IN_DIM + q * 8;
#pragma unroll
    for (int c = 0; c < 4; ++c) {
      const float4 w0 = *(const float4*)(wr + c * 32);
      const float4 w1 = *(const float4*)(wr + c * 32 + 4);
      bfr[c] = pack8(w0, w1);
    }
  }
  // A fragments
  int m = mb + n16;
  if (m >= N) m = N - 1;  // clamped read; stores guarded
  bf16x8 afr[4];
  {
    const float* hr = h + (size_t)m * IN_DIM + q * 8;
#pragma unroll
    for (int c = 0; c < 4; ++c) {
      const float4 a0 = *(const float4*)(hr + c * 32);
      const float4 a1 = *(const float4*)(hr + c * 32 + 4);
      afr[c] = pack8(a0, a1);
    }
  }

  f32x4 acc = {0.f, 0.f, 0.f, 0.f};
#pragma unroll
  for (int c = 0; c < 4; ++c)
    acc = __builtin_amdgcn_mfma_f32_16x16x32_bf16(afr[c], bfr[c], acc, 0, 0, 0);

  // per-node sum of squares over this wave's 16 outs: butterfly over n16 lanes
  float sq[4];
#pragma unroll
  for (int r = 0; r < 4; ++r) {
    float s = acc[r] * acc[r];
    s += SWZ(s, 0x041F);  // xor1
    s += SWZ(s, 0x081F);  // xor2
    s += SWZ(s, 0x101F);  // xor4
    s += SWZ(s, 0x201F);  // xor8 -> sum over 16 cols, all lanes
    sq[r] = s;
  }
  if (n16 == 0) {
#pragma unroll
    for (int r = 0; r < 4; ++r) pss[oh][ng * 16 + q * 4 + r] = sq[r];
  }

  // store raw z as bf16: pack col pairs via xor1 swizzle, even-n16 lanes store dwords
#pragma unroll
  for (int r = 0; r < 4; ++r) {
    const float partner = SWZ(acc[r], 0x041F);
    const int node = mb + q * 4 + r;
    if (((n16 & 1) == 0) && node < N) {
      const unsigned pk = (unsigned)f2bf(acc[r]) | ((unsigned)f2bf(partner) << 16);
      *(unsigned*)(zhb + (size_t)node * OUT_DIM + oh * 16 + n16) = pk;
    }
  }

  __syncthreads();
  if (tid < 32) {
    const int node = blockIdx.x * 32 + tid;
    const float ss = pss[0][tid] + pss[1][tid];
    if (node < N) invn[node] = 1.0f / fmaxf(sqrtf(ss), EPS);
  }
}

// Kernel 2: wave = 4 nodes (2 half-wave pairs), lane l5 = (edge e=l5>>1,
// chunk c=l5&1 of 16 outs). ALL loads for both pairs hoisted (2x memory
// parallelism). cos = dot(zs,zd)*inv_s*inv_d on raw bf16 z; weight = ex
// (raw z needs no un-normalization). Dot: 16 fma + 1 swizzle; denom: 4
// swizzles; edge->out transpose via private LDS slot per pair (no barrier).
// beta*(cos-1) bounded in [-2b,0] -> no softmax max pass.
__global__ __launch_bounds__(256) void edge_kernel(
    const unsigned short* __restrict__ zhb, const float* __restrict__ invn,
    const int* __restrict__ src, const float* __restrict__ beta_p,
    float* __restrict__ out, int N) {
  __shared__ float xp[16 * DEG * 36];  // 4 waves x 2 pairs x 2 halves slots = 36.9 KB

  const int tid = threadIdx.x;
  const int l5 = tid & 31, half = (tid >> 5) & 1, wv = tid >> 6;
  const int e = l5 >> 1, c = l5 & 1;
  const int base = (blockIdx.x * 4 + wv) * 4;
  if (base >= N) return;  // wave-uniform exit
  const float beta = *beta_p;

  int n_[2], ne_[2];
#pragma unroll
  for (int p = 0; p < 2; ++p) {
    n_[p] = base + p * 2 + half;
    ne_[p] = (n_[p] < N) ? n_[p] : N - 1;
  }

  // ---- hoisted loads for both pairs ----
  int se_[2]; float is_[2], id_[2];
  uint4 sa_[2], sb_[2], da_[2], db_[2];
#pragma unroll
  for (int p = 0; p < 2; ++p) {
    se_[p] = src[(size_t)ne_[p] * DEG + e];
    is_[p] = invn[se_[p]];
    id_[p] = invn[ne_[p]];
    const uint4* zs4 = (const uint4*)(zhb + (size_t)se_[p] * OUT_DIM) + c * 2;
    sa_[p] = zs4[0]; sb_[p] = zs4[1];
    const uint4* zd4 = (const uint4*)(zhb + (size_t)ne_[p] * OUT_DIM) + c * 2;
    da_[p] = zd4[0]; db_[p] = zd4[1];
  }

#pragma unroll
  for (int p = 0; p < 2; ++p) {
    float vs[16], vd[16];
    const uint4 sa = sa_[p], sb = sb_[p], da = da_[p], db = db_[p];
    vs[0] = bflo(sa.x);  vs[1] = bfhi(sa.x);  vs[2] = bflo(sa.y);  vs[3] = bfhi(sa.y);
    vs[4] = bflo(sa.z);  vs[5] = bfhi(sa.z);  vs[6] = bflo(sa.w);  vs[7] = bfhi(sa.w);
    vs[8] = bflo(sb.x);  vs[9] = bfhi(sb.x);  vs[10] = bflo(sb.y); vs[11] = bfhi(sb.y);
    vs[12] = bflo(sb.z); vs[13] = bfhi(sb.z); vs[14] = bflo(sb.w); vs[15] = bfhi(sb.w);
    vd[0] = bflo(da.x);  vd[1] = bfhi(da.x);  vd[2] = bflo(da.y);  vd[3] = bfhi(da.y);
    vd[4] = bflo(da.z);  vd[5] = bfhi(da.z);  vd[6] = bflo(da.w);  vd[7] = bfhi(da.w);
    vd[8] = bflo(db.x);  vd[9] = bfhi(db.x);  vd[10] = bflo(db.y); vd[11] = bfhi(db.y);
    vd[12] = bflo(db.z); vd[13] = bfhi(db.z); vd[14] = bflo(db.w); vd[15] = bfhi(db.w);

    float pr = vs[0] * vd[0];
#pragma unroll
    for (int i = 1; i < 16; ++i) pr = fmaf(vs[i], vd[i], pr);
    pr += SWZ(pr, 0x041F);  // xor1: other 16-chunk -> full raw dot

    const float cosv = pr * is_[p] * id_[p];
    const float ex = __expf(beta * (cosv - 1.0f));

    float den = ex;
    den += SWZ(den, 0x081F);
    den += SWZ(den, 0x101F);
    den += SWZ(den, 0x201F);
    den += SWZ(den, 0x401F);  // sum over 16 edges
    const float rd = 1.0f / den;

    float* slot = xp + ((wv * 2 + p) * 2 + half) * (DEG * 36);
    float4* wp = (float4*)(slot + e * 36 + c * 16);
    wp[0] = make_float4(ex * vs[0], ex * vs[1], ex * vs[2], ex * vs[3]);
    wp[1] = make_float4(ex * vs[4], ex * vs[5], ex * vs[6], ex * vs[7]);
    wp[2] = make_float4(ex * vs[8], ex * vs[9], ex * vs[10], ex * vs[11]);
    wp[3] = make_float4(ex * vs[12], ex * vs[13], ex * vs[14], ex * vs[15]);
    // same-wave LDS RAW: compiler inserts lgkmcnt wait; no barrier

    float s = 0.f;
#pragma unroll
    for (int e2 = 0; e2 < DEG; ++e2)
      s += slot[e2 * 36 + l5];  // bank (4e2+l5)%32, conflict-free per read

    if (n_[p] < N) out[(size_t)n_[p] * OUT_DIM + l5] = s * rd;
  }
}

extern "C" void kernel_launch(void* const* d_in, const int* in_sizes, int n_in,
                              void* d_out, int out_size, void* d_ws, size_t ws_size,
                              hipStream_t stream) {
  const float* h    = (const float*)d_in[0];
  const float* W    = (const float*)d_in[1];
  const float* beta = (const float*)d_in[2];
  const int*   src  = (const int*)d_in[3];
  // d_in[4] = dst == arange(E)//DEG -> node n owns edges [n*DEG, (n+1)*DEG)

  const int N = in_sizes[0] / IN_DIM;

  unsigned short* zhb = (unsigned short*)d_ws;       // N*32 bf16 = 6.4 MB (raw z)
  float* invn = (float*)(zhb + (size_t)N * OUT_DIM); // N floats

  const int bl1 = (N + 31) / 32;  // 32 nodes per block
  gemm_norm_kernel<<<bl1, 256, 0, stream>>>(h, W, zhb, invn, N);

  const int bl2 = (N + 15) / 16;  // 16 nodes per block (4 waves x 4 nodes)
  edge_kernel<<<bl2, 256, 0, stream>>>(zhb, invn, src, beta, (float*)d_out, N);
}